// Round 3
// baseline (373.774 us; speedup 1.0000x reference)
//
#include <hip/hip_runtime.h>
#include <hip/hip_fp16.h>
#include <math.h>

typedef _Float16 half8  __attribute__((ext_vector_type(8)));
typedef _Float16 half2v __attribute__((ext_vector_type(2)));
typedef float   floatx4 __attribute__((ext_vector_type(4)));

#define ROWS   16384
#define DIM    128
#define KCODES 8192
#define NSPLIT 16
#define MTILE  256
#define NT     32
#define NCHUNK ((KCODES / NSPLIT) / NT)   // 16
#define NCAND  (2 * NSPLIT)               // 32 rescore candidates per row

__device__ __forceinline__ void async_copy16(const _Float16* src, _Float16* dst_lds) {
  __builtin_amdgcn_global_load_lds((const __attribute__((address_space(1))) void*)src,
                                   (__attribute__((address_space(3))) void*)dst_lds,
                                   16, 0, 0);
}

// ---------------- kernel 1: fused codebook prep + LN-once ----------------
// blocks [0, KCODES/4): codebook fp16 hi/lo split + e2 (stores -0.5*||e||^2).
// blocks [KCODES/4, +ROWS/4): LayerNorm x -> xnh (fp16), computed ONCE here
// instead of NSPLIT times inside argmin (round-1 measured ~11us per duplicate).
__global__ __launch_bounds__(256) void prep_kernel(
    const float* __restrict__ cb, const float* __restrict__ x,
    _Float16* __restrict__ ehg, _Float16* __restrict__ elg,
    float* __restrict__ e2g, _Float16* __restrict__ xnh)
{
  int tid = threadIdx.x;
  int L = tid & 63;
  int bx = blockIdx.x;
  if (bx < KCODES / 4) {
    int row = bx * 4 + (tid >> 6);
    float2 v = ((const float2*)(cb + (size_t)row * DIM))[L];
    float s2 = v.x * v.x + v.y * v.y;
    #pragma unroll
    for (int m = 1; m < 64; m <<= 1) s2 += __shfl_xor(s2, m);
    if (L == 0) e2g[row] = -0.5f * s2;
    _Float16 h0 = (_Float16)v.x, h1 = (_Float16)v.y;
    half2v hi = {h0, h1};
    half2v lo = {(_Float16)(v.x - (float)h0), (_Float16)(v.y - (float)h1)};
    ((half2v*)(ehg + (size_t)row * DIM))[L] = hi;
    ((half2v*)(elg + (size_t)row * DIM))[L] = lo;
  } else {
    int row = (bx - KCODES / 4) * 4 + (tid >> 6);
    float2 xv = ((const float2*)(x + (size_t)row * DIM))[L];
    float s = xv.x + xv.y;
    #pragma unroll
    for (int m = 1; m < 64; m <<= 1) s += __shfl_xor(s, m);
    float mu = s * (1.0f / 128.0f);
    float dx = xv.x - mu, dy = xv.y - mu;
    float s2 = dx * dx + dy * dy;
    #pragma unroll
    for (int m = 1; m < 64; m <<= 1) s2 += __shfl_xor(s2, m);
    float rstd = 1.0f / sqrtf(s2 * (1.0f / 128.0f) + 1e-5f);
    half2v hv = {(_Float16)(dx * rstd), (_Float16)(dy * rstd)};
    ((half2v*)(xnh + (size_t)row * DIM))[L] = hv;
  }
}

// ---------------- kernel 2: argmin via 2-term fp16 MFMA ----------------
// 256-thread blocks (4 waves), 32KB LDS, grid = 64 mtiles x 16 splits = 1024
// -> 4 blocks/CU co-resident (4 waves/SIMD), four independent barrier domains
// overlap each other's stalls (round 0-2 showed 1-block/CU latency-bound:
// MfmaUtil 32%, VALUBusy 50%, occupancy 21%, both pipes idle most of the time).
// Math unchanged from proven round-2: t = ah.bh + ah.bl - e2/2, top-2 + exact
// rescore downstream. e2 for chunk ch+1 prefetched into regs during chunk ch.
__global__ __launch_bounds__(256, 4) void argmin_kernel(
    const _Float16* __restrict__ xnh, const _Float16* __restrict__ ehg,
    const _Float16* __restrict__ elg, const float* __restrict__ e2g,
    int* __restrict__ i1p, int* __restrict__ i2p)
{
  // [buf][arr(hi/lo)][code n][128 halfs]; chunk kcs within a row holds global
  // chunk kc = kcs ^ (n&7) (16B chunks). 32 KB total.
  __shared__ _Float16 ebuf[2][2][NT][128];

  int tid = threadIdx.x;
  int w   = tid >> 6;      // 0..3
  int L   = tid & 63;
  int c   = L & 15;        // MFMA A-row / B-col lane index
  int q   = L >> 4;        // quad

  int bx = blockIdx.x;
  int mt = bx & (ROWS / MTILE - 1);   // 0..63
  int ns = bx >> 6;                   // 0..15

  int rowbase = mt * MTILE + w * 64;

  // A fragments from precomputed fp16 LN output
  half8 ah[4][4];
  #pragma unroll
  for (int g = 0; g < 4; ++g) {
    const _Float16* xr = xnh + (size_t)(rowbase + g * 16 + c) * DIM;
    #pragma unroll
    for (int ks = 0; ks < 4; ++ks)
      ah[g][ks] = *(const half8*)(xr + ks * 32 + q * 8);
  }

  // top-2 tracking: maximize t
  float b1[4][4], b2[4][4]; int i1[4][4], i2[4][4];
  #pragma unroll
  for (int g = 0; g < 4; ++g)
    #pragma unroll
    for (int r = 0; r < 4; ++r) {
      b1[g][r] = -3.4e38f; b2[g][r] = -3.4e38f;
      i1[g][r] = 0; i2[g][r] = 0;
    }

  int code0 = ns * (KCODES / NSPLIT);
  _Float16* lbase = &ebuf[0][0][0][0];

  // ---- async staging: 1024 16B chunks per tile, 4 per thread ----
  auto stage = [&](int ch, int p) {
    int cbase = code0 + ch * NT;
    _Float16* lb = lbase + (size_t)p * 2 * NT * 128;
    #pragma unroll
    for (int it = 0; it < 4; ++it) {
      int cid = it * 256 + tid;          // 0..1023
      int arr = cid >> 9;                // 0 = hi, 1 = lo
      int lc  = cid & 511;
      int n   = lc >> 4;                 // 0..31
      int kcs = lc & 15;                 // LDS slot chunk
      int kc  = kcs ^ (n & 7);           // global chunk (inverse swizzle)
      const _Float16* g = (arr ? elg : ehg) + (size_t)(cbase + n) * DIM + kc * 8;
      async_copy16(g, lb + (size_t)cid * 8);
    }
  };

  stage(0, 0);
  float e2c[2], e2n[2];
  e2c[0] = e2g[code0 + c];
  e2c[1] = e2g[code0 + 16 + c];
  __syncthreads();

  for (int ch = 0; ch < NCHUNK; ++ch) {
    int p = ch & 1;
    int cbase = code0 + ch * NT;
    if (ch + 1 < NCHUNK) {
      stage(ch + 1, p ^ 1);
      e2n[0] = e2g[cbase + NT + c];        // prefetch next chunk's e2
      e2n[1] = e2g[cbase + NT + 16 + c];
    }

    #pragma unroll
    for (int s = 0; s < 2; ++s) {
      int n = s * 16 + c;                  // n & 7 == c & 7
      half8 bh[4], bl[4];
      #pragma unroll
      for (int ks = 0; ks < 4; ++ks) {
        int slot = ((ks * 4 + q) ^ (c & 7)) * 8;
        bh[ks] = *(const half8*)&ebuf[p][0][n][slot];
        bl[ks] = *(const half8*)&ebuf[p][1][n][slot];
      }
      int nn = cbase + n;
      #pragma unroll
      for (int g = 0; g < 4; ++g) {
        floatx4 acc = {e2c[s], e2c[s], e2c[s], e2c[s]};
        #pragma unroll
        for (int ks = 0; ks < 4; ++ks) {
          acc = __builtin_amdgcn_mfma_f32_16x16x32_f16(ah[g][ks], bh[ks], acc, 0, 0, 0);
          acc = __builtin_amdgcn_mfma_f32_16x16x32_f16(ah[g][ks], bl[ks], acc, 0, 0, 0);
        }
        #pragma unroll
        for (int r = 0; r < 4; ++r) {
          float t = acc[r];
          bool gt1 = t > b1[g][r];
          bool gt2 = t > b2[g][r];
          b2[g][r] = gt1 ? b1[g][r] : (gt2 ? t  : b2[g][r]);
          i2[g][r] = gt1 ? i1[g][r] : (gt2 ? nn : i2[g][r]);
          b1[g][r] = gt1 ? t  : b1[g][r];
          i1[g][r] = gt1 ? nn : i1[g][r];
        }
      }
    }
    __syncthreads();   // drains async stage of ch+1; protects buf reuse
    e2c[0] = e2n[0]; e2c[1] = e2n[1];
  }

  // reduce top-2 over the 16 col-lanes of each quad
  #pragma unroll
  for (int m = 1; m < 16; m <<= 1)
    #pragma unroll
    for (int g = 0; g < 4; ++g)
      #pragma unroll
      for (int r = 0; r < 4; ++r) {
        float ob1 = __shfl_xor(b1[g][r], m); int oi1 = __shfl_xor(i1[g][r], m);
        float ob2 = __shfl_xor(b2[g][r], m); int oi2 = __shfl_xor(i2[g][r], m);
        if (ob1 > b1[g][r]) {
          float nb2 = (b1[g][r] >= ob2) ? b1[g][r] : ob2;
          int   ni2 = (b1[g][r] >= ob2) ? i1[g][r] : oi2;
          b1[g][r] = ob1; i1[g][r] = oi1;
          b2[g][r] = nb2; i2[g][r] = ni2;
        } else {
          float nb2 = (ob1 >= b2[g][r]) ? ob1 : b2[g][r];
          int   ni2 = (ob1 >= b2[g][r]) ? oi1 : i2[g][r];
          b2[g][r] = nb2; i2[g][r] = ni2;
        }
      }
  if (c == 0) {
    #pragma unroll
    for (int g = 0; g < 4; ++g)
      #pragma unroll
      for (int r = 0; r < 4; ++r) {
        int row = rowbase + g * 16 + q * 4 + r;
        i1p[(size_t)row * NSPLIT + ns] = i1[g][r];
        i2p[(size_t)row * NSPLIT + ns] = i2[g][r];
      }
  }
}

// ---------------- kernel 3: parallel exact fp32 rescore + gather + loss ----------------
// 32 candidates/row rescored wave-parallel: lane -> candidate (L&31), two
// lane-halves each cover 64 of the 128 dims; one shfl_xor(32) completes dots.
__global__ __launch_bounds__(256) void gather_loss_kernel(
    const float* __restrict__ x, const float* __restrict__ cb,
    const float* __restrict__ e2g,
    const int* __restrict__ i1p, const int* __restrict__ i2p,
    float* __restrict__ out_q, float* __restrict__ out_ind,
    float* __restrict__ row_loss)
{
  int tid = threadIdx.x;
  int L = tid & 63;
  int row = blockIdx.x * 4 + (tid >> 6);

  int k  = L & 31;
  int qd = L >> 5;

  // lanes 0..15 carry split L's top-1; lanes 16..31 split (L-16)'s top-2
  int ci = 0;
  if (L < 16)      ci = i1p[(size_t)row * NSPLIT + L];
  else if (L < 32) ci = i2p[(size_t)row * NSPLIT + (L - 16)];
  int idxk = __shfl(ci, k);

  // LayerNorm stats (exact fp32)
  float2 xv = ((const float2*)(x + (size_t)row * DIM))[L];
  float s = xv.x + xv.y;
  #pragma unroll
  for (int m = 1; m < 64; m <<= 1) s += __shfl_xor(s, m);
  float mu = s * (1.0f / 128.0f);
  float dx = xv.x - mu, dy = xv.y - mu;
  float s2 = dx * dx + dy * dy;
  #pragma unroll
  for (int m = 1; m < 64; m <<= 1) s2 += __shfl_xor(s2, m);
  float rstd = 1.0f / sqrtf(s2 * (1.0f / 128.0f) + 1e-5f);

  // exact dot over this lane's 64-dim half of candidate idxk
  const float4* xr4 = (const float4*)(x  + (size_t)row  * DIM);
  const float4* er4 = (const float4*)(cb + (size_t)idxk * DIM);
  float p = 0.f;
  #pragma unroll
  for (int j = 0; j < 16; ++j) {
    float4 a = xr4[qd * 16 + j];
    float4 e = er4[qd * 16 + j];
    p += (a.x - mu) * e.x + (a.y - mu) * e.y + (a.z - mu) * e.z + (a.w - mu) * e.w;
  }
  p *= rstd;
  p += __shfl_xor(p, 32);
  float t = p + e2g[idxk];        // e2g = -0.5*||e||^2 exact

  // argmax over the 32 candidates (tie -> smaller index)
  int bi = idxk;
  #pragma unroll
  for (int m = 1; m < 32; m <<= 1) {
    float ot = __shfl_xor(t, m);
    int   oi = __shfl_xor(bi, m);
    if (ot > t || (ot == t && oi < bi)) { t = ot; bi = oi; }
  }

  // gather winner row + loss
  float2 qv = ((const float2*)(cb + (size_t)bi * DIM))[L];
  ((float2*)out_q)[(size_t)row * 64 + L] = qv;
  float xn0 = dx * rstd, xn1 = dy * rstd;
  float e0 = qv.x - xn0, e1 = qv.y - xn1;
  float le = e0 * e0 + e1 * e1;
  #pragma unroll
  for (int m = 1; m < 64; m <<= 1) le += __shfl_xor(le, m);
  if (L == 0) {
    row_loss[row] = le;
    out_ind[row] = (float)bi;
  }
}

// ---------------- kernel 4: deterministic loss reduction ----------------
__global__ __launch_bounds__(1024) void loss_reduce_kernel(
    const float* __restrict__ row_loss, float* __restrict__ out_loss)
{
  __shared__ float sm[1024];
  int tid = threadIdx.x;
  float s = 0.f;
  for (int i = tid; i < ROWS; i += 1024) s += row_loss[i];
  sm[tid] = s; __syncthreads();
  for (int st = 512; st > 0; st >>= 1) {
    if (tid < st) sm[tid] += sm[tid + st];
    __syncthreads();
  }
  if (tid == 0) *out_loss = sm[0] * (1.0f / (float)(ROWS * DIM));
}

extern "C" void kernel_launch(void* const* d_in, const int* in_sizes, int n_in,
                              void* d_out, int out_size, void* d_ws, size_t ws_size,
                              hipStream_t stream)
{
  const float* x  = (const float*)d_in[0];   // [4,4096,128] fp32
  const float* cb = (const float*)d_in[1];   // [8192,128]  fp32

  char* ws = (char*)d_ws;
  _Float16* ehg      = (_Float16*)(ws + 0);          // 2 MB
  _Float16* elg      = (_Float16*)(ws + 2097152);    // 2 MB
  float*    e2g      = (float*)   (ws + 4194304);    // 32 KB
  int*      i1p      = (int*)     (ws + 4227072);    // 1 MB
  int*      i2p      = (int*)     (ws + 5275648);    // 1 MB
  float*    row_loss = (float*)   (ws + 6324224);    // 64 KB

  float* out_q    = (float*)d_out;                   // 16384*128
  float* out_ind  = out_q + (size_t)ROWS * DIM;      // 16384 (as float)
  float* out_loss = out_ind + ROWS;                  // 1

  // xnh (fp16 LN output, 4 MB) lives in the out_q region: written by prep,
  // read by argmin, and out_q itself is only written afterwards by gather.
  _Float16* xnh = (_Float16*)out_q;

  prep_kernel<<<KCODES / 4 + ROWS / 4, 256, 0, stream>>>(cb, x, ehg, elg, e2g, xnh);
  argmin_kernel<<<(ROWS / MTILE) * NSPLIT, 256, 0, stream>>>(xnh, ehg, elg, e2g, i1p, i2p);
  gather_loss_kernel<<<ROWS / 4, 256, 0, stream>>>(x, cb, e2g, i1p, i2p, out_q, out_ind, row_loss);
  loss_reduce_kernel<<<1, 1024, 0, stream>>>(row_loss, out_loss);
}

// Round 4
// 205.825 us; speedup vs baseline: 1.8160x; 1.8160x over previous
//
#include <hip/hip_runtime.h>
#include <hip/hip_fp16.h>
#include <math.h>

typedef _Float16 half8  __attribute__((ext_vector_type(8)));
typedef _Float16 half2v __attribute__((ext_vector_type(2)));
typedef float   floatx4 __attribute__((ext_vector_type(4)));

#define ROWS   16384
#define DIM    128
#define KCODES 8192
#define NSPLIT 16
#define MTILE  256
#define NT     32
#define NCHUNK ((KCODES / NSPLIT) / NT)   // 16
#define NCAND  (2 * NSPLIT)               // 32 rescore candidates per row

__device__ __forceinline__ void async_copy16(const _Float16* src, _Float16* dst_lds) {
  __builtin_amdgcn_global_load_lds((const __attribute__((address_space(1))) void*)src,
                                   (__attribute__((address_space(3))) void*)dst_lds,
                                   16, 0, 0);
}

// ---------------- kernel 1: fused codebook prep + LN-once ----------------
// blocks [0, KCODES/4): codebook fp16 hi/lo split + e2 (stores -0.5*||e||^2).
// blocks [KCODES/4, +ROWS/4): LayerNorm x -> xnh (fp16), computed ONCE here
// instead of NSPLIT times inside argmin.
__global__ __launch_bounds__(256) void prep_kernel(
    const float* __restrict__ cb, const float* __restrict__ x,
    _Float16* __restrict__ ehg, _Float16* __restrict__ elg,
    float* __restrict__ e2g, _Float16* __restrict__ xnh)
{
  int tid = threadIdx.x;
  int L = tid & 63;
  int bx = blockIdx.x;
  if (bx < KCODES / 4) {
    int row = bx * 4 + (tid >> 6);
    float2 v = ((const float2*)(cb + (size_t)row * DIM))[L];
    float s2 = v.x * v.x + v.y * v.y;
    #pragma unroll
    for (int m = 1; m < 64; m <<= 1) s2 += __shfl_xor(s2, m);
    if (L == 0) e2g[row] = -0.5f * s2;
    _Float16 h0 = (_Float16)v.x, h1 = (_Float16)v.y;
    half2v hi = {h0, h1};
    half2v lo = {(_Float16)(v.x - (float)h0), (_Float16)(v.y - (float)h1)};
    ((half2v*)(ehg + (size_t)row * DIM))[L] = hi;
    ((half2v*)(elg + (size_t)row * DIM))[L] = lo;
  } else {
    int row = (bx - KCODES / 4) * 4 + (tid >> 6);
    float2 xv = ((const float2*)(x + (size_t)row * DIM))[L];
    float s = xv.x + xv.y;
    #pragma unroll
    for (int m = 1; m < 64; m <<= 1) s += __shfl_xor(s, m);
    float mu = s * (1.0f / 128.0f);
    float dx = xv.x - mu, dy = xv.y - mu;
    float s2 = dx * dx + dy * dy;
    #pragma unroll
    for (int m = 1; m < 64; m <<= 1) s2 += __shfl_xor(s2, m);
    float rstd = 1.0f / sqrtf(s2 * (1.0f / 128.0f) + 1e-5f);
    half2v hv = {(_Float16)(dx * rstd), (_Float16)(dy * rstd)};
    ((half2v*)(xnh + (size_t)row * DIM))[L] = hv;
  }
}

// ---------------- kernel 2: argmin via 2-term fp16 MFMA ----------------
// 256-thread blocks (4 waves), 32KB LDS, grid = 64 mtiles x 16 splits = 1024.
// Target: 4 blocks/CU (4 waves/SIMD), four independent barrier domains
// overlapping each other's stalls.
// __launch_bounds__ CAUTION (round-3 post-mortem): 2nd arg 4 imposed a
// 64-VGPR cap; demand ~124 -> ~60 regs spilled -> FETCH_SIZE 704MB, 2.8x
// slower. (256,2) caps at >=128: no spills, natural ~124 still allows
// 4 blocks/CU. Do NOT raise the 2nd arg.
__global__ __launch_bounds__(256, 2) void argmin_kernel(
    const _Float16* __restrict__ xnh, const _Float16* __restrict__ ehg,
    const _Float16* __restrict__ elg, const float* __restrict__ e2g,
    int* __restrict__ i1p, int* __restrict__ i2p)
{
  // [buf][arr(hi/lo)][code n][128 halfs]; chunk kcs within a row holds global
  // chunk kc = kcs ^ (n&7) (16B chunks). 32 KB total.
  __shared__ _Float16 ebuf[2][2][NT][128];

  int tid = threadIdx.x;
  int w   = tid >> 6;      // 0..3
  int L   = tid & 63;
  int c   = L & 15;        // MFMA A-row / B-col lane index
  int q   = L >> 4;        // quad

  int bx = blockIdx.x;
  int mt = bx & (ROWS / MTILE - 1);   // 0..63
  int ns = bx >> 6;                   // 0..15

  int rowbase = mt * MTILE + w * 64;

  // A fragments from precomputed fp16 LN output
  half8 ah[4][4];
  #pragma unroll
  for (int g = 0; g < 4; ++g) {
    const _Float16* xr = xnh + (size_t)(rowbase + g * 16 + c) * DIM;
    #pragma unroll
    for (int ks = 0; ks < 4; ++ks)
      ah[g][ks] = *(const half8*)(xr + ks * 32 + q * 8);
  }

  // top-2 tracking: maximize t
  float b1[4][4], b2[4][4]; int i1[4][4], i2[4][4];
  #pragma unroll
  for (int g = 0; g < 4; ++g)
    #pragma unroll
    for (int r = 0; r < 4; ++r) {
      b1[g][r] = -3.4e38f; b2[g][r] = -3.4e38f;
      i1[g][r] = 0; i2[g][r] = 0;
    }

  int code0 = ns * (KCODES / NSPLIT);
  _Float16* lbase = &ebuf[0][0][0][0];

  // ---- async staging: 1024 16B chunks per tile, 4 per thread ----
  auto stage = [&](int ch, int p) {
    int cbase = code0 + ch * NT;
    _Float16* lb = lbase + (size_t)p * 2 * NT * 128;
    #pragma unroll
    for (int it = 0; it < 4; ++it) {
      int cid = it * 256 + tid;          // 0..1023
      int arr = cid >> 9;                // 0 = hi, 1 = lo
      int lc  = cid & 511;
      int n   = lc >> 4;                 // 0..31
      int kcs = lc & 15;                 // LDS slot chunk
      int kc  = kcs ^ (n & 7);           // global chunk (inverse swizzle)
      const _Float16* g = (arr ? elg : ehg) + (size_t)(cbase + n) * DIM + kc * 8;
      async_copy16(g, lb + (size_t)cid * 8);
    }
  };

  stage(0, 0);
  float e2c[2], e2n[2];
  e2c[0] = e2g[code0 + c];
  e2c[1] = e2g[code0 + 16 + c];
  __syncthreads();

  for (int ch = 0; ch < NCHUNK; ++ch) {
    int p = ch & 1;
    int cbase = code0 + ch * NT;
    if (ch + 1 < NCHUNK) {
      stage(ch + 1, p ^ 1);
      e2n[0] = e2g[cbase + NT + c];        // prefetch next chunk's e2
      e2n[1] = e2g[cbase + NT + 16 + c];
    }

    #pragma unroll
    for (int s = 0; s < 2; ++s) {
      int n = s * 16 + c;                  // n & 7 == c & 7
      half8 bh[4], bl[4];
      #pragma unroll
      for (int ks = 0; ks < 4; ++ks) {
        int slot = ((ks * 4 + q) ^ (c & 7)) * 8;
        bh[ks] = *(const half8*)&ebuf[p][0][n][slot];
        bl[ks] = *(const half8*)&ebuf[p][1][n][slot];
      }
      int nn = cbase + n;
      #pragma unroll
      for (int g = 0; g < 4; ++g) {
        floatx4 acc = {e2c[s], e2c[s], e2c[s], e2c[s]};
        #pragma unroll
        for (int ks = 0; ks < 4; ++ks) {
          acc = __builtin_amdgcn_mfma_f32_16x16x32_f16(ah[g][ks], bh[ks], acc, 0, 0, 0);
          acc = __builtin_amdgcn_mfma_f32_16x16x32_f16(ah[g][ks], bl[ks], acc, 0, 0, 0);
        }
        #pragma unroll
        for (int r = 0; r < 4; ++r) {
          float t = acc[r];
          bool gt1 = t > b1[g][r];
          bool gt2 = t > b2[g][r];
          b2[g][r] = gt1 ? b1[g][r] : (gt2 ? t  : b2[g][r]);
          i2[g][r] = gt1 ? i1[g][r] : (gt2 ? nn : i2[g][r]);
          b1[g][r] = gt1 ? t  : b1[g][r];
          i1[g][r] = gt1 ? nn : i1[g][r];
        }
      }
    }
    __syncthreads();   // drains async stage of ch+1; protects buf reuse
    e2c[0] = e2n[0]; e2c[1] = e2n[1];
  }

  // reduce top-2 over the 16 col-lanes of each quad
  #pragma unroll
  for (int m = 1; m < 16; m <<= 1)
    #pragma unroll
    for (int g = 0; g < 4; ++g)
      #pragma unroll
      for (int r = 0; r < 4; ++r) {
        float ob1 = __shfl_xor(b1[g][r], m); int oi1 = __shfl_xor(i1[g][r], m);
        float ob2 = __shfl_xor(b2[g][r], m); int oi2 = __shfl_xor(i2[g][r], m);
        if (ob1 > b1[g][r]) {
          float nb2 = (b1[g][r] >= ob2) ? b1[g][r] : ob2;
          int   ni2 = (b1[g][r] >= ob2) ? i1[g][r] : oi2;
          b1[g][r] = ob1; i1[g][r] = oi1;
          b2[g][r] = nb2; i2[g][r] = ni2;
        } else {
          float nb2 = (ob1 >= b2[g][r]) ? ob1 : b2[g][r];
          int   ni2 = (ob1 >= b2[g][r]) ? oi1 : i2[g][r];
          b2[g][r] = nb2; i2[g][r] = ni2;
        }
      }
  if (c == 0) {
    #pragma unroll
    for (int g = 0; g < 4; ++g)
      #pragma unroll
      for (int r = 0; r < 4; ++r) {
        int row = rowbase + g * 16 + q * 4 + r;
        i1p[(size_t)row * NSPLIT + ns] = i1[g][r];
        i2p[(size_t)row * NSPLIT + ns] = i2[g][r];
      }
  }
}

// ---------------- kernel 3: parallel exact fp32 rescore + gather + loss ----------------
// 32 candidates/row rescored wave-parallel: lane -> candidate (L&31), two
// lane-halves each cover 64 of the 128 dims; one shfl_xor(32) completes dots.
__global__ __launch_bounds__(256) void gather_loss_kernel(
    const float* __restrict__ x, const float* __restrict__ cb,
    const float* __restrict__ e2g,
    const int* __restrict__ i1p, const int* __restrict__ i2p,
    float* __restrict__ out_q, float* __restrict__ out_ind,
    float* __restrict__ row_loss)
{
  int tid = threadIdx.x;
  int L = tid & 63;
  int row = blockIdx.x * 4 + (tid >> 6);

  int k  = L & 31;
  int qd = L >> 5;

  // lanes 0..15 carry split L's top-1; lanes 16..31 split (L-16)'s top-2
  int ci = 0;
  if (L < 16)      ci = i1p[(size_t)row * NSPLIT + L];
  else if (L < 32) ci = i2p[(size_t)row * NSPLIT + (L - 16)];
  int idxk = __shfl(ci, k);

  // LayerNorm stats (exact fp32)
  float2 xv = ((const float2*)(x + (size_t)row * DIM))[L];
  float s = xv.x + xv.y;
  #pragma unroll
  for (int m = 1; m < 64; m <<= 1) s += __shfl_xor(s, m);
  float mu = s * (1.0f / 128.0f);
  float dx = xv.x - mu, dy = xv.y - mu;
  float s2 = dx * dx + dy * dy;
  #pragma unroll
  for (int m = 1; m < 64; m <<= 1) s2 += __shfl_xor(s2, m);
  float rstd = 1.0f / sqrtf(s2 * (1.0f / 128.0f) + 1e-5f);

  // exact dot over this lane's 64-dim half of candidate idxk
  const float4* xr4 = (const float4*)(x  + (size_t)row  * DIM);
  const float4* er4 = (const float4*)(cb + (size_t)idxk * DIM);
  float p = 0.f;
  #pragma unroll
  for (int j = 0; j < 16; ++j) {
    float4 a = xr4[qd * 16 + j];
    float4 e = er4[qd * 16 + j];
    p += (a.x - mu) * e.x + (a.y - mu) * e.y + (a.z - mu) * e.z + (a.w - mu) * e.w;
  }
  p *= rstd;
  p += __shfl_xor(p, 32);
  float t = p + e2g[idxk];        // e2g = -0.5*||e||^2 exact

  // argmax over the 32 candidates (tie -> smaller index)
  int bi = idxk;
  #pragma unroll
  for (int m = 1; m < 32; m <<= 1) {
    float ot = __shfl_xor(t, m);
    int   oi = __shfl_xor(bi, m);
    if (ot > t || (ot == t && oi < bi)) { t = ot; bi = oi; }
  }

  // gather winner row + loss
  float2 qv = ((const float2*)(cb + (size_t)bi * DIM))[L];
  ((float2*)out_q)[(size_t)row * 64 + L] = qv;
  float xn0 = dx * rstd, xn1 = dy * rstd;
  float e0 = qv.x - xn0, e1 = qv.y - xn1;
  float le = e0 * e0 + e1 * e1;
  #pragma unroll
  for (int m = 1; m < 64; m <<= 1) le += __shfl_xor(le, m);
  if (L == 0) {
    row_loss[row] = le;
    out_ind[row] = (float)bi;
  }
}

// ---------------- kernel 4: deterministic loss reduction ----------------
__global__ __launch_bounds__(1024) void loss_reduce_kernel(
    const float* __restrict__ row_loss, float* __restrict__ out_loss)
{
  __shared__ float sm[1024];
  int tid = threadIdx.x;
  float s = 0.f;
  for (int i = tid; i < ROWS; i += 1024) s += row_loss[i];
  sm[tid] = s; __syncthreads();
  for (int st = 512; st > 0; st >>= 1) {
    if (tid < st) sm[tid] += sm[tid + st];
    __syncthreads();
  }
  if (tid == 0) *out_loss = sm[0] * (1.0f / (float)(ROWS * DIM));
}

extern "C" void kernel_launch(void* const* d_in, const int* in_sizes, int n_in,
                              void* d_out, int out_size, void* d_ws, size_t ws_size,
                              hipStream_t stream)
{
  const float* x  = (const float*)d_in[0];   // [4,4096,128] fp32
  const float* cb = (const float*)d_in[1];   // [8192,128]  fp32

  char* ws = (char*)d_ws;
  _Float16* ehg      = (_Float16*)(ws + 0);          // 2 MB
  _Float16* elg      = (_Float16*)(ws + 2097152);    // 2 MB
  float*    e2g      = (float*)   (ws + 4194304);    // 32 KB
  int*      i1p      = (int*)     (ws + 4227072);    // 1 MB
  int*      i2p      = (int*)     (ws + 5275648);    // 1 MB
  float*    row_loss = (float*)   (ws + 6324224);    // 64 KB

  float* out_q    = (float*)d_out;                   // 16384*128
  float* out_ind  = out_q + (size_t)ROWS * DIM;      // 16384 (as float)
  float* out_loss = out_ind + ROWS;                  // 1

  // xnh (fp16 LN output, 4 MB) lives in the out_q region: written by prep,
  // read by argmin, and out_q itself is only written afterwards by gather.
  _Float16* xnh = (_Float16*)out_q;

  prep_kernel<<<KCODES / 4 + ROWS / 4, 256, 0, stream>>>(cb, x, ehg, elg, e2g, xnh);
  argmin_kernel<<<(ROWS / MTILE) * NSPLIT, 256, 0, stream>>>(xnh, ehg, elg, e2g, i1p, i2p);
  gather_loss_kernel<<<ROWS / 4, 256, 0, stream>>>(x, cb, e2g, i1p, i2p, out_q, out_ind, row_loss);
  loss_reduce_kernel<<<1, 1024, 0, stream>>>(row_loss, out_loss);
}

// Round 5
// 179.091 us; speedup vs baseline: 2.0871x; 1.1493x over previous
//
#include <hip/hip_runtime.h>
#include <hip/hip_fp16.h>
#include <math.h>

typedef _Float16 half8  __attribute__((ext_vector_type(8)));
typedef _Float16 half2v __attribute__((ext_vector_type(2)));
typedef float   floatx4 __attribute__((ext_vector_type(4)));

#define ROWS   16384
#define DIM    128
#define KCODES 8192
#define NSPLIT 16
#define MTILE  256
#define NT     32
#define NCHUNK ((KCODES / NSPLIT) / NT)   // 16
#define KSPLIT (KCODES / NSPLIT)          // 512
#define DELTA  0.5f                       // prefilter margin >> 2*pass1 error bound (~0.08)

__device__ __forceinline__ void async_copy16(const void* src, void* dst_lds) {
  __builtin_amdgcn_global_load_lds((const __attribute__((address_space(1))) void*)src,
                                   (__attribute__((address_space(3))) void*)dst_lds,
                                   16, 0, 0);
}

// ---------------- kernel 1: fused codebook prep + LN-once ----------------
__global__ __launch_bounds__(256) void prep_kernel(
    const float* __restrict__ cb, const float* __restrict__ x,
    _Float16* __restrict__ ehg, _Float16* __restrict__ elg,
    float* __restrict__ e2g, _Float16* __restrict__ xnh)
{
  int tid = threadIdx.x;
  int L = tid & 63;
  int bx = blockIdx.x;
  if (bx < KCODES / 4) {
    int row = bx * 4 + (tid >> 6);
    float2 v = ((const float2*)(cb + (size_t)row * DIM))[L];
    float s2 = v.x * v.x + v.y * v.y;
    #pragma unroll
    for (int m = 1; m < 64; m <<= 1) s2 += __shfl_xor(s2, m);
    if (L == 0) e2g[row] = -0.5f * s2;
    _Float16 h0 = (_Float16)v.x, h1 = (_Float16)v.y;
    half2v hi = {h0, h1};
    half2v lo = {(_Float16)(v.x - (float)h0), (_Float16)(v.y - (float)h1)};
    ((half2v*)(ehg + (size_t)row * DIM))[L] = hi;
    ((half2v*)(elg + (size_t)row * DIM))[L] = lo;
  } else {
    int row = (bx - KCODES / 4) * 4 + (tid >> 6);
    float2 xv = ((const float2*)(x + (size_t)row * DIM))[L];
    float s = xv.x + xv.y;
    #pragma unroll
    for (int m = 1; m < 64; m <<= 1) s += __shfl_xor(s, m);
    float mu = s * (1.0f / 128.0f);
    float dx = xv.x - mu, dy = xv.y - mu;
    float s2 = dx * dx + dy * dy;
    #pragma unroll
    for (int m = 1; m < 64; m <<= 1) s2 += __shfl_xor(s2, m);
    float rstd = 1.0f / sqrtf(s2 * (1.0f / 128.0f) + 1e-5f);
    half2v hv = {(_Float16)(dx * rstd), (_Float16)(dy * rstd)};
    ((half2v*)(xnh + (size_t)row * DIM))[L] = hv;
  }
}

// ---------------- kernel 2: argmin, counted-vmcnt pipelined ----------------
// r0/r2/r4 post-mortem: dur invariant (91-97us) across 3x MFMA-work changes
// => per-chunk fixed cost dominates = __syncthreads' vmcnt(0) drain of the
// async stage, with ~2 waves/SIMD to hide nothing. Fix (T3/T4): 3-buffer LDS
// ring, raw s_barrier + s_waitcnt vmcnt(4) (never 0 in loop); stage(ch+2)
// issued AFTER the barrier (safe: barrier proves compute(ch) done before
// buf ch%3 is rewritten). e2 staged to LDS once so vmcnt counting stays exact.
// LDS 50KB -> 3 blocks/CU.  __launch_bounds__ CAUTION (r3): 2nd arg 4 imposed
// a 64-VGPR cap -> massive spills; keep (256,2).
__global__ __launch_bounds__(256, 2) void argmin_kernel(
    const _Float16* __restrict__ xnh, const _Float16* __restrict__ ehg,
    const _Float16* __restrict__ elg, const float* __restrict__ e2g,
    float* __restrict__ b1p, int* __restrict__ i1p,
    float* __restrict__ b2p, int* __restrict__ i2p)
{
  // [buf][arr(hi/lo)][code n][128 halfs]; chunk kcs within a row holds global
  // chunk kc = kcs ^ (n&7) (16B chunks). 3 x 16KB ring.
  __shared__ _Float16 ebuf[3][2][NT][128];
  __shared__ float e2lds[KSPLIT];

  int tid = threadIdx.x;
  int w   = tid >> 6;      // 0..3
  int L   = tid & 63;
  int c   = L & 15;        // MFMA A-row / B-col lane index
  int q   = L >> 4;        // quad

  int bx = blockIdx.x;
  int mt = bx & (ROWS / MTILE - 1);   // 0..63
  int ns = bx >> 6;                   // 0..15

  int rowbase = mt * MTILE + w * 64;
  int code0 = ns * KSPLIT;
  _Float16* lbase = &ebuf[0][0][0][0];

  // ---- async staging: 1024 16B chunks per tile, 4 per thread ----
  auto stage = [&](int ch, int p) {
    int cbase = code0 + ch * NT;
    _Float16* lb = lbase + (size_t)p * 2 * NT * 128;
    #pragma unroll
    for (int it = 0; it < 4; ++it) {
      int cid = it * 256 + tid;          // 0..1023
      int arr = cid >> 9;                // 0 = hi, 1 = lo
      int lc  = cid & 511;
      int n   = lc >> 4;                 // 0..31
      int kcs = lc & 15;                 // LDS slot chunk
      int kc  = kcs ^ (n & 7);           // global chunk (inverse swizzle)
      const _Float16* g = (arr ? elg : ehg) + (size_t)(cbase + n) * DIM + kc * 8;
      async_copy16(g, lb + (size_t)cid * 8);
    }
  };

  // A fragments from precomputed fp16 LN output (regular loads; compiler
  // tracks their waits independently of our counted staging vmcnts)
  half8 ah[4][4];
  #pragma unroll
  for (int g = 0; g < 4; ++g) {
    const _Float16* xr = xnh + (size_t)(rowbase + g * 16 + c) * DIM;
    #pragma unroll
    for (int ks = 0; ks < 4; ++ks)
      ah[g][ks] = *(const half8*)(xr + ks * 32 + q * 8);
  }

  // e2 for this split -> LDS (threads 0..127 issue one 16B chunk; 2KB)
  if (tid < KSPLIT / 4) async_copy16(e2g + code0 + tid * 4, e2lds + tid * 4);
  // prologue stages for chunks 0 and 1
  stage(0, 0);
  stage(1, 1);

  // top-2 tracking: maximize t = dot - e2/2
  float b1[4][4], b2[4][4]; int i1[4][4], i2[4][4];
  #pragma unroll
  for (int g = 0; g < 4; ++g)
    #pragma unroll
    for (int r = 0; r < 4; ++r) {
      b1[g][r] = -3.4e38f; b2[g][r] = -3.4e38f;
      i1[g][r] = 0; i2[g][r] = 0;
    }

  int bc = 0;   // ring buffer holding chunk ch
  int bs = 2;   // ring buffer for chunk ch+2
  for (int ch = 0; ch < NCHUNK; ++ch) {
    // wait: stage(ch) landed (at most ch+1's 4 loads still outstanding)
    if (ch + 1 < NCHUNK) asm volatile("s_waitcnt vmcnt(4)" ::: "memory");
    else                 asm volatile("s_waitcnt vmcnt(0)" ::: "memory");
    __builtin_amdgcn_s_barrier();
    if (ch + 2 < NCHUNK) stage(ch + 2, bs);

    int cbase = code0 + ch * NT;
    float e2h[2];
    e2h[0] = e2lds[ch * NT + c];
    e2h[1] = e2lds[ch * NT + 16 + c];

    #pragma unroll
    for (int s = 0; s < 2; ++s) {
      int n = s * 16 + c;                  // n & 7 == c & 7
      half8 bh[4], bl[4];
      #pragma unroll
      for (int ks = 0; ks < 4; ++ks) {
        int slot = ((ks * 4 + q) ^ (c & 7)) * 8;
        bh[ks] = *(const half8*)&ebuf[bc][0][n][slot];
        bl[ks] = *(const half8*)&ebuf[bc][1][n][slot];
      }
      int nn = cbase + n;
      #pragma unroll
      for (int g = 0; g < 4; ++g) {
        floatx4 acc = {e2h[s], e2h[s], e2h[s], e2h[s]};
        #pragma unroll
        for (int ks = 0; ks < 4; ++ks) {
          acc = __builtin_amdgcn_mfma_f32_16x16x32_f16(ah[g][ks], bh[ks], acc, 0, 0, 0);
          acc = __builtin_amdgcn_mfma_f32_16x16x32_f16(ah[g][ks], bl[ks], acc, 0, 0, 0);
        }
        #pragma unroll
        for (int r = 0; r < 4; ++r) {
          float t = acc[r];
          bool gt1 = t > b1[g][r];
          bool gt2 = t > b2[g][r];
          b2[g][r] = gt1 ? b1[g][r] : (gt2 ? t  : b2[g][r]);
          i2[g][r] = gt1 ? i1[g][r] : (gt2 ? nn : i2[g][r]);
          b1[g][r] = gt1 ? t  : b1[g][r];
          i1[g][r] = gt1 ? nn : i1[g][r];
        }
      }
    }
    bc = (bc == 2) ? 0 : bc + 1;
    bs = (bs == 2) ? 0 : bs + 1;
  }

  // reduce top-2 over the 16 col-lanes of each quad
  #pragma unroll
  for (int m = 1; m < 16; m <<= 1)
    #pragma unroll
    for (int g = 0; g < 4; ++g)
      #pragma unroll
      for (int r = 0; r < 4; ++r) {
        float ob1 = __shfl_xor(b1[g][r], m); int oi1 = __shfl_xor(i1[g][r], m);
        float ob2 = __shfl_xor(b2[g][r], m); int oi2 = __shfl_xor(i2[g][r], m);
        if (ob1 > b1[g][r]) {
          float nb2 = (b1[g][r] >= ob2) ? b1[g][r] : ob2;
          int   ni2 = (b1[g][r] >= ob2) ? i1[g][r] : oi2;
          b1[g][r] = ob1; i1[g][r] = oi1;
          b2[g][r] = nb2; i2[g][r] = ni2;
        } else {
          float nb2 = (ob1 >= b2[g][r]) ? ob1 : b2[g][r];
          int   ni2 = (ob1 >= b2[g][r]) ? oi1 : i2[g][r];
          b2[g][r] = nb2; i2[g][r] = ni2;
        }
      }
  if (c == 0) {
    #pragma unroll
    for (int g = 0; g < 4; ++g)
      #pragma unroll
      for (int r = 0; r < 4; ++r) {
        int row = rowbase + g * 16 + q * 4 + r;
        b1p[(size_t)row * NSPLIT + ns] = b1[g][r];
        i1p[(size_t)row * NSPLIT + ns] = i1[g][r];
        b2p[(size_t)row * NSPLIT + ns] = b2[g][r];
        i2p[(size_t)row * NSPLIT + ns] = i2[g][r];
      }
  }
}

// ---------------- kernel 3: prefiltered exact rescore + gather + loss ----------------
// 32 candidates/row; lane k = candidate, two lane-halves cover 64 dims each.
// Prefilter: skip candidates whose pass-1 score < max - DELTA (sound: pass-1
// error bound ~0.04 << DELTA/2). Typically 1-3 survivors -> ~10x less gather
// traffic than rescoring all 32.
__global__ __launch_bounds__(256) void gather_loss_kernel(
    const float* __restrict__ x, const float* __restrict__ cb,
    const float* __restrict__ e2g,
    const float* __restrict__ b1p, const int* __restrict__ i1p,
    const float* __restrict__ b2p, const int* __restrict__ i2p,
    float* __restrict__ out_q, float* __restrict__ out_ind,
    float* __restrict__ row_loss)
{
  int tid = threadIdx.x;
  int L = tid & 63;
  int row = blockIdx.x * 4 + (tid >> 6);

  int k  = L & 31;
  int qd = L >> 5;

  // lanes 0..15: split L top-1; lanes 16..31: split (L-16) top-2
  int ci = 0; float cv = -3.4e38f;
  if (L < 16)      { ci = i1p[(size_t)row * NSPLIT + L];        cv = b1p[(size_t)row * NSPLIT + L]; }
  else if (L < 32) { ci = i2p[(size_t)row * NSPLIT + (L - 16)]; cv = b2p[(size_t)row * NSPLIT + (L - 16)]; }
  int   idxk = __shfl(ci, k);
  float tvk  = __shfl(cv, k);

  // pass-1 max over the 32 candidates
  float tmax = tvk;
  #pragma unroll
  for (int m = 1; m < 32; m <<= 1) tmax = fmaxf(tmax, __shfl_xor(tmax, m));
  bool keep = tvk >= tmax - DELTA;

  // LayerNorm stats (exact fp32)
  float2 xv = ((const float2*)(x + (size_t)row * DIM))[L];
  float s = xv.x + xv.y;
  #pragma unroll
  for (int m = 1; m < 64; m <<= 1) s += __shfl_xor(s, m);
  float mu = s * (1.0f / 128.0f);
  float dx = xv.x - mu, dy = xv.y - mu;
  float s2 = dx * dx + dy * dy;
  #pragma unroll
  for (int m = 1; m < 64; m <<= 1) s2 += __shfl_xor(s2, m);
  float rstd = 1.0f / sqrtf(s2 * (1.0f / 128.0f) + 1e-5f);

  // exact dot over this lane's 64-dim half of candidate idxk (survivors only)
  float t = -3.4e38f;
  float p = 0.f;
  if (keep) {
    const float4* xr4 = (const float4*)(x  + (size_t)row  * DIM);
    const float4* er4 = (const float4*)(cb + (size_t)idxk * DIM);
    #pragma unroll
    for (int j = 0; j < 16; ++j) {
      float4 a = xr4[qd * 16 + j];
      float4 e = er4[qd * 16 + j];
      p += (a.x - mu) * e.x + (a.y - mu) * e.y + (a.z - mu) * e.z + (a.w - mu) * e.w;
    }
    p *= rstd;
  }
  p += __shfl_xor(p, 32);          // both halves of k share 'keep'
  if (keep) t = p + e2g[idxk];     // e2g = -0.5*||e||^2 exact

  // argmax over the 32 candidates (tie -> smaller index)
  int bi = idxk;
  #pragma unroll
  for (int m = 1; m < 32; m <<= 1) {
    float ot = __shfl_xor(t, m);
    int   oi = __shfl_xor(bi, m);
    if (ot > t || (ot == t && oi < bi)) { t = ot; bi = oi; }
  }

  // gather winner row + loss
  float2 qv = ((const float2*)(cb + (size_t)bi * DIM))[L];
  ((float2*)out_q)[(size_t)row * 64 + L] = qv;
  float xn0 = dx * rstd, xn1 = dy * rstd;
  float e0 = qv.x - xn0, e1 = qv.y - xn1;
  float le = e0 * e0 + e1 * e1;
  #pragma unroll
  for (int m = 1; m < 64; m <<= 1) le += __shfl_xor(le, m);
  if (L == 0) {
    row_loss[row] = le;
    out_ind[row] = (float)bi;
  }
}

// ---------------- kernel 4: deterministic loss reduction ----------------
__global__ __launch_bounds__(1024) void loss_reduce_kernel(
    const float* __restrict__ row_loss, float* __restrict__ out_loss)
{
  __shared__ float sm[1024];
  int tid = threadIdx.x;
  float s = 0.f;
  for (int i = tid; i < ROWS; i += 1024) s += row_loss[i];
  sm[tid] = s; __syncthreads();
  for (int st = 512; st > 0; st >>= 1) {
    if (tid < st) sm[tid] += sm[tid + st];
    __syncthreads();
  }
  if (tid == 0) *out_loss = sm[0] * (1.0f / (float)(ROWS * DIM));
}

extern "C" void kernel_launch(void* const* d_in, const int* in_sizes, int n_in,
                              void* d_out, int out_size, void* d_ws, size_t ws_size,
                              hipStream_t stream)
{
  const float* x  = (const float*)d_in[0];   // [4,4096,128] fp32
  const float* cb = (const float*)d_in[1];   // [8192,128]  fp32

  char* ws = (char*)d_ws;
  _Float16* ehg      = (_Float16*)(ws + 0);          // 2 MB
  _Float16* elg      = (_Float16*)(ws + 2097152);    // 2 MB
  float*    e2g      = (float*)   (ws + 4194304);    // 32 KB
  int*      i1p      = (int*)     (ws + 4227072);    // 1 MB
  int*      i2p      = (int*)     (ws + 5275648);    // 1 MB
  float*    b1p      = (float*)   (ws + 6324224);    // 1 MB
  float*    b2p      = (float*)   (ws + 7372800);    // 1 MB
  float*    row_loss = (float*)   (ws + 8421376);    // 64 KB

  float* out_q    = (float*)d_out;                   // 16384*128
  float* out_ind  = out_q + (size_t)ROWS * DIM;      // 16384 (as float)
  float* out_loss = out_ind + ROWS;                  // 1

  // xnh (fp16 LN output, 4 MB) lives in the out_q region: written by prep,
  // read by argmin; out_q itself is only written afterwards by gather.
  _Float16* xnh = (_Float16*)out_q;

  prep_kernel<<<KCODES / 4 + ROWS / 4, 256, 0, stream>>>(cb, x, ehg, elg, e2g, xnh);
  argmin_kernel<<<(ROWS / MTILE) * NSPLIT, 256, 0, stream>>>(xnh, ehg, elg, e2g, b1p, i1p, b2p, i2p);
  gather_loss_kernel<<<ROWS / 4, 256, 0, stream>>>(x, cb, e2g, b1p, i1p, b2p, i2p, out_q, out_ind, row_loss);
  loss_reduce_kernel<<<1, 1024, 0, stream>>>(row_loss, out_loss);
}